// Round 1
// 179.309 us; speedup vs baseline: 1.0175x; 1.0175x over previous
//
#include <hip/hip_runtime.h>

// SubjectConditionalLinear: y[b,n,o] = sum_h x[b,n,h] * W[sid[b],o,h] + bias[sid[b],o]
// x: [32,512,1024] f32, subject_id: [32] i32, weight: [8,1024,1024] f32, bias: [8,1024] f32
// out: [32,512,1024] f32
//
// R5: port gemm to the 256x256 8-phase template (T3+T4 counted-vmcnt + T5 setprio),
// keeping the XOR k-chunk swizzle (T2-equivalent, 0 bank conflicts in R4).
// 512 threads / 8 waves (2Mx4N), BK=64, 128 KiB LDS (2 dbuf x (A 32K + B 32K)).
// Staging in interleaved half-tiles 1.5-2 K-tiles ahead; vmcnt(6)/vmcnt(8) counted
// waits once per K-tile phase 0/3 (never drain-0 in steady state).
// Grid 256 blocks (1/CU), XCD-grouped: xcd = bid&7 owns batches 4*xcd..4*xcd+3.

constexpr int S_DIM = 8;
constexpr int O_DIM = 1024;
constexpr int H_DIM = 1024;
constexpr int B_DIM = 32;
constexpr int N_DIM = 512;

constexpr int BM = 256;
constexpr int BN = 256;
constexpr int BK = 64;
constexpr int NKT = H_DIM / BK;  // 16 K-tiles

constexpr long long X_ELEMS = (long long)B_DIM * N_DIM * H_DIM;   // 16,777,216
constexpr size_t XB_BYTES = (size_t)X_ELEMS * 2;                  // 32 MiB

typedef short bf16x8 __attribute__((ext_vector_type(8)));
typedef float f32x4 __attribute__((ext_vector_type(4)));
typedef float f32x2 __attribute__((ext_vector_type(2)));
typedef __bf16 bf16x2 __attribute__((ext_vector_type(2)));

__device__ __forceinline__ unsigned int cvt_pk_bf16(float a, float b) {
  f32x2 v;
  v[0] = a;
  v[1] = b;
  bf16x2 r = __builtin_convertvector(v, bf16x2);  // v_cvt_pk_bf16_f32
  return __builtin_bit_cast(unsigned int, r);
}

__device__ __forceinline__ void gload_lds16(const void* g, void* l) {
  __builtin_amdgcn_global_load_lds(
      (const __attribute__((address_space(1))) unsigned int*)g,
      (__attribute__((address_space(3))) unsigned int*)l, 16, 0, 0);
}

// ---------- Phase 1: fp32 -> bf16 convert (x and all 8 weight matrices) ----
__global__ __launch_bounds__(256) void cvt_kernel(
    const float* __restrict__ x, const float* __restrict__ w,
    unsigned short* __restrict__ xb, unsigned short* __restrict__ wb) {
  const int blk = blockIdx.x;
  const float* src;
  unsigned short* dst;
  long long base;
  if (blk < 4096) {
    src = x; dst = xb; base = (long long)blk * 4096;
  } else {
    src = w; dst = wb; base = (long long)(blk - 4096) * 4096;
  }
  const long long e0 = base + threadIdx.x * 4;
#pragma unroll
  for (int c = 0; c < 4; ++c) {
    const f32x4 v = __builtin_nontemporal_load((const f32x4*)(src + e0 + c * 1024));
    uint2 u;
    u.x = cvt_pk_bf16(v[0], v[1]);
    u.y = cvt_pk_bf16(v[2], v[3]);
    *(uint2*)(dst + e0 + c * 1024) = u;
  }
}

// ---------- Phase 2: bf16 MFMA GEMM, 256^2 8-phase schedule ----------------
#define BAR() __builtin_amdgcn_s_barrier()
#define VMW(N) asm volatile("s_waitcnt vmcnt(" #N ")" ::: "memory")
#define LGKM0()                                            \
  do {                                                     \
    asm volatile("s_waitcnt lgkmcnt(0)" ::: "memory");     \
    __builtin_amdgcn_sched_barrier(0);                     \
  } while (0)

// A-fragment quad: rows wr*128 + (MB..MB+3)*16 + lcol, both kk halves.
#define LDA4(ABUF, MB)                                                   \
  do {                                                                   \
    _Pragma("unroll") for (int m_ = 0; m_ < 4; ++m_) {                   \
      const int ar_ = wr * 128 + ((MB) + m_) * 16 + lcol;                \
      const unsigned short* ap_ = (ABUF) + ar_ * BK;                     \
      af[m_][0] = *(const bf16x8*)(ap_ + (pc0 << 3));                    \
      af[m_][1] = *(const bf16x8*)(ap_ + ((pc0 ^ 4) << 3));              \
    }                                                                    \
  } while (0)

// B-fragment pair: rows wc*64 + (NB..NB+1)*16 + lcol, both kk halves.
#define LDB2(BBUF, NB)                                                   \
  do {                                                                   \
    _Pragma("unroll") for (int n_ = 0; n_ < 2; ++n_) {                   \
      const int br_ = wc * 64 + ((NB) + n_) * 16 + lcol;                 \
      const unsigned short* bp_ = (BBUF) + br_ * BK;                     \
      bfr[n_][0] = *(const bf16x8*)(bp_ + (pc0 << 3));                   \
      bfr[n_][1] = *(const bf16x8*)(bp_ + ((pc0 ^ 4) << 3));             \
    }                                                                    \
  } while (0)

// One C-quadrant x K=64: 4m x 2n x 2kk = 16 MFMA.
#define MM4(MB, NB)                                                         \
  do {                                                                      \
    _Pragma("unroll") for (int m_ = 0; m_ < 4; ++m_)                        \
    _Pragma("unroll") for (int n_ = 0; n_ < 2; ++n_)                        \
    _Pragma("unroll") for (int x_ = 0; x_ < 2; ++x_)                        \
      acc[(MB) + m_][(NB) + n_] = __builtin_amdgcn_mfma_f32_16x16x32_bf16(  \
          af[m_][x_], bfr[n_][x_], acc[(MB) + m_][(NB) + n_], 0, 0, 0);     \
  } while (0)

// Stage A half H (rows {H*64+w*8+rl, 128+H*64+w*8+rl}) of K-tile KT into DST.
#define STAGE_A(H, DST, KT)                                                 \
  do {                                                                      \
    gload_lds16(agA + (size_t)((H) * 64) * H_DIM + (KT) * 64,               \
                (DST) + ((H) * 64 + wid * 8) * BK);                         \
    gload_lds16(agA + (size_t)((H) * 64 + 128) * H_DIM + (KT) * 64,         \
                (DST) + ((H) * 64 + 128 + wid * 8) * BK);                   \
  } while (0)

// Stage B strip S (rows q*64 + S*32 + sub*8 + rl) of K-tile KT into DST.
#define STAGE_B(S, DST, KT)                                                 \
  do {                                                                      \
    gload_lds16(bgB0 + (size_t)((S) * 32) * H_DIM + (KT) * 64,              \
                (DST) + (bq0 + (S) * 32) * BK);                             \
    gload_lds16(bgB1 + (size_t)((S) * 32) * H_DIM + (KT) * 64,              \
                (DST) + (bq1 + (S) * 32) * BK);                             \
  } while (0)

__global__ __launch_bounds__(512, 2) void scl_gemm(
    const unsigned short* __restrict__ xb, const int* __restrict__ subject_id,
    const unsigned short* __restrict__ wb, const float* __restrict__ bias,
    float* __restrict__ out) {
  __shared__ __align__(16) unsigned short As[2][BM * BK];  // 64 KiB
  __shared__ __align__(16) unsigned short Bs[2][BN * BK];  // 64 KiB

  const int tid = threadIdx.x;
  const int lane = tid & 63;
  const int wid = tid >> 6;   // 0..7
  const int wr = wid >> 2;    // 0..1  (M half)
  const int wc = wid & 3;     // 0..3  (N quarter)
  const int lcol = lane & 15;
  const int lq = lane >> 4;   // 0..3
  const int rl = lane >> 3;   // 0..7 (staging row-in-group)
  const int pc0 = lq ^ (lane & 7);  // phys chunk for kk=0 (XOR swizzle)

  // XCD-grouped bijective block map: xcd = bid&7 owns batches 4*xcd..4*xcd+3.
  const int bid = blockIdx.x;
  const int b = (bid & 7) * 4 + ((bid >> 3) & 3);
  const int t = bid >> 5;          // 0..7
  const int n0 = (t & 1) * BM;
  const int o0 = (t >> 1) * BN;
  const int sid = subject_id[b];

  // Staging global bases. Lane L of a wave covers phys chunk L&7 of row rl;
  // logical chunk = (L&7)^rl (row&7 == rl since all row bases are x8).
  const int skc = ((lane & 7) ^ rl) << 3;
  const unsigned short* agA =
      xb + (size_t)(b * N_DIM + n0 + wid * 8 + rl) * H_DIM + skc;
  const int bq0 = ((wid * 2) >> 2) * 64 + ((wid * 2) & 3) * 8;
  const int bq1 = ((wid * 2 + 1) >> 2) * 64 + ((wid * 2 + 1) & 3) * 8;
  const unsigned short* bgB0 =
      wb + (size_t)(sid * O_DIM + o0 + bq0 + rl) * H_DIM + skc;
  const unsigned short* bgB1 =
      wb + (size_t)(sid * O_DIM + o0 + bq1 + rl) * H_DIM + skc;

  unsigned short* const As0 = &As[0][0];
  unsigned short* const As1 = &As[1][0];
  unsigned short* const Bs0 = &Bs[0][0];
  unsigned short* const Bs1 = &Bs[1][0];

  f32x4 acc[8][4];
#pragma unroll
  for (int mi = 0; mi < 8; ++mi)
#pragma unroll
    for (int ni = 0; ni < 4; ++ni) {
      f32x4 z = {0.f, 0.f, 0.f, 0.f};
      acc[mi][ni] = z;
    }

  bf16x8 af[4][2];
  bfr_decl:;
  bf16x8 bfr[2][2];

  // Prologue: emulate steady-state stage stream order:
  // A_q0(0), B_s0(0), A_q1(0), B_s1(0), A_q0(1), B_s0(1)  -> 12 loads.
  STAGE_A(0, As0, 0);
  STAGE_B(0, Bs0, 0);
  STAGE_A(1, As0, 0);
  STAGE_B(1, Bs0, 0);
  STAGE_A(0, As1, 1);
  STAGE_B(0, Bs1, 1);
  VMW(8);  // oldest 4 loads (A_q0(0), B_s0(0)) landed
  BAR();

#pragma unroll
  for (int kt = 0; kt < NKT; ++kt) {
    unsigned short* const Ac = (kt & 1) ? As1 : As0;
    unsigned short* const Bc = (kt & 1) ? Bs1 : Bs0;
    unsigned short* const Ao = (kt & 1) ? As0 : As1;
    unsigned short* const Bo = (kt & 1) ? Bs0 : Bs1;

    // ---- P0: Q(lo-m, lo-n). Reads A_q0(kt), B_s0(kt). Stage A_q1(kt+1).
    LDA4(Ac, 0);
    LDB2(Bc, 0);
    if (kt + 1 < NKT) {
      STAGE_A(1, Ao, kt + 1);
      VMW(6);  // B_s1(kt) landed; {A_q0,B_s0}(kt+1), A_q1(kt+1) may fly
    } else {
      VMW(0);
    }
    BAR();
    LGKM0();
    __builtin_amdgcn_s_setprio(1);
    MM4(0, 0);
    __builtin_amdgcn_s_setprio(0);
    BAR();

    // ---- P1: Q(lo-m, hi-n). Reads B_s1(kt). Stage B_s1(kt+1).
    LDB2(Bc, 2);
    if (kt + 1 < NKT) STAGE_B(1, Bo, kt + 1);
    BAR();
    LGKM0();
    __builtin_amdgcn_s_setprio(1);
    MM4(0, 2);
    __builtin_amdgcn_s_setprio(0);
    BAR();

    // ---- P2: Q(hi-m, lo-n). Reads A_q1(kt), re-reads B_s0(kt).
    //      A_q0(kt) dead -> stage A_q0(kt+2) into current buffer.
    LDA4(Ac, 4);
    LDB2(Bc, 0);
    if (kt + 2 < NKT) STAGE_A(0, Ac, kt + 2);
    BAR();
    LGKM0();
    __builtin_amdgcn_s_setprio(1);
    MM4(4, 0);
    __builtin_amdgcn_s_setprio(0);
    BAR();

    // ---- P3: Q(hi-m, hi-n). Re-reads B_s1(kt).
    //      B_s0(kt) dead -> stage B_s0(kt+2) into current buffer.
    LDB2(Bc, 2);
    if (kt + 2 < NKT) {
      STAGE_B(0, Bc, kt + 2);
      VMW(8);  // {A_q0,B_s0}(kt+1) landed; 4 newer halves may fly
    } else if (kt + 2 == NKT) {
      VMW(4);  // tail: only {A_q1,B_s1}(kt+1) still in flight
    }
    BAR();
    LGKM0();
    __builtin_amdgcn_s_setprio(1);
    MM4(4, 2);
    __builtin_amdgcn_s_setprio(0);
    BAR();
  }

  // Epilogue: C/D layout col = lane&15, row = (lane>>4)*4 + reg.
  float bv[4];
#pragma unroll
  for (int ni = 0; ni < 4; ++ni)
    bv[ni] = bias[sid * O_DIM + o0 + wc * 64 + ni * 16 + lcol];

  float* outb =
      out + (size_t)(b * N_DIM + n0 + wr * 128) * O_DIM + o0 + wc * 64 + lcol;
#pragma unroll
  for (int mi = 0; mi < 8; ++mi) {
#pragma unroll
    for (int r = 0; r < 4; ++r) {
      float* orow = outb + (size_t)(mi * 16 + lq * 4 + r) * O_DIM;
#pragma unroll
      for (int ni = 0; ni < 4; ++ni)
        orow[ni * 16] = acc[mi][ni][r] + bv[ni];
    }
  }
}

extern "C" void kernel_launch(void* const* d_in, const int* in_sizes, int n_in,
                              void* d_out, int out_size, void* d_ws, size_t ws_size,
                              hipStream_t stream) {
  const float* x = (const float*)d_in[0];
  const int* subject_id = (const int*)d_in[1];
  const float* weight = (const float*)d_in[2];
  const float* bias = (const float*)d_in[3];
  float* out = (float*)d_out;

  unsigned short* xb = (unsigned short*)d_ws;                       // 32 MiB
  unsigned short* wb = (unsigned short*)((char*)d_ws + XB_BYTES);   // 16 MiB

  cvt_kernel<<<6144, 256, 0, stream>>>(x, weight, xb, wb);

  scl_gemm<<<256, 512, 0, stream>>>(xb, subject_id, wb, bias, out);
}

// Round 2
// 177.618 us; speedup vs baseline: 1.0272x; 1.0095x over previous
//
#include <hip/hip_runtime.h>

// SubjectConditionalLinear: y[b,n,o] = sum_h x[b,n,h] * W[sid[b],o,h] + bias[sid[b],o]
// x: [32,512,1024] f32, subject_id: [32] i32, weight: [8,1024,1024] f32, bias: [8,1024] f32
// out: [32,512,1024] f32
//
// R6: hoisted-read single-barrier pipeline. R5's 8-phase was SERIAL per phase
// (reads -> BAR -> MFMA -> BAR): LDS drain (1150c) + MFMA (620c) added, matching
// the measured 7500c/K-tile. Now each phase's fragment reads are issued in the
// PREVIOUS phase's tail (after its MFMA), so LDS service overlaps MFMA, and
// lgkm0 at phase top is ~free. Snake order Q00->Q01->Q11->Q10 + persistent
// bfL/bfH kills the B re-read: 24 ds_read_b128/thread/K-tile (floor).
// One barrier per phase (64 total). Wait ledger (loads, 2 per STAGE):
//   steady: VMW(8)@P2-tail covers next P3-tail reads; VMW(4)@P3-tail covers
//   next P0/P1-tail reads; every overwrite >=1 full barrier after readers'
//   lgkm0. Tail: kt=14 -> VMW(4)/VMW(0); kt=15 -> none.

constexpr int S_DIM = 8;
constexpr int O_DIM = 1024;
constexpr int H_DIM = 1024;
constexpr int B_DIM = 32;
constexpr int N_DIM = 512;

constexpr int BM = 256;
constexpr int BN = 256;
constexpr int BK = 64;
constexpr int NKT = H_DIM / BK;  // 16 K-tiles

constexpr long long X_ELEMS = (long long)B_DIM * N_DIM * H_DIM;   // 16,777,216
constexpr size_t XB_BYTES = (size_t)X_ELEMS * 2;                  // 32 MiB

typedef short bf16x8 __attribute__((ext_vector_type(8)));
typedef float f32x4 __attribute__((ext_vector_type(4)));
typedef float f32x2 __attribute__((ext_vector_type(2)));
typedef __bf16 bf16x2 __attribute__((ext_vector_type(2)));

__device__ __forceinline__ unsigned int cvt_pk_bf16(float a, float b) {
  f32x2 v;
  v[0] = a;
  v[1] = b;
  bf16x2 r = __builtin_convertvector(v, bf16x2);  // v_cvt_pk_bf16_f32
  return __builtin_bit_cast(unsigned int, r);
}

__device__ __forceinline__ void gload_lds16(const void* g, void* l) {
  __builtin_amdgcn_global_load_lds(
      (const __attribute__((address_space(1))) unsigned int*)g,
      (__attribute__((address_space(3))) unsigned int*)l, 16, 0, 0);
}

// ---------- Phase 1: fp32 -> bf16 convert (x and all 8 weight matrices) ----
__global__ __launch_bounds__(256) void cvt_kernel(
    const float* __restrict__ x, const float* __restrict__ w,
    unsigned short* __restrict__ xb, unsigned short* __restrict__ wb) {
  const int blk = blockIdx.x;
  const float* src;
  unsigned short* dst;
  long long base;
  if (blk < 4096) {
    src = x; dst = xb; base = (long long)blk * 4096;
  } else {
    src = w; dst = wb; base = (long long)(blk - 4096) * 4096;
  }
  const long long e0 = base + threadIdx.x * 4;
#pragma unroll
  for (int c = 0; c < 4; ++c) {
    const f32x4 v = __builtin_nontemporal_load((const f32x4*)(src + e0 + c * 1024));
    uint2 u;
    u.x = cvt_pk_bf16(v[0], v[1]);
    u.y = cvt_pk_bf16(v[2], v[3]);
    *(uint2*)(dst + e0 + c * 1024) = u;
  }
}

// ---------- Phase 2: bf16 MFMA GEMM, hoisted-read pipeline -----------------
#define BAR() __builtin_amdgcn_s_barrier()
#define SB0() __builtin_amdgcn_sched_barrier(0)
#define VMW(N) asm volatile("s_waitcnt vmcnt(" #N ")" ::: "memory")
#define LGKM0()                                            \
  do {                                                     \
    asm volatile("s_waitcnt lgkmcnt(0)" ::: "memory");     \
    __builtin_amdgcn_sched_barrier(0);                     \
  } while (0)

// A-fragment quad into DST: rows wr*128 + (MB..MB+3)*16 + lcol, both kk halves.
#define LDA4T(DST, ABUF, MB)                                             \
  do {                                                                   \
    _Pragma("unroll") for (int m_ = 0; m_ < 4; ++m_) {                   \
      const int ar_ = wr * 128 + ((MB) + m_) * 16 + lcol;                \
      const unsigned short* ap_ = (ABUF) + ar_ * BK;                     \
      DST[m_][0] = *(const bf16x8*)(ap_ + (pc0 << 3));                   \
      DST[m_][1] = *(const bf16x8*)(ap_ + ((pc0 ^ 4) << 3));             \
    }                                                                    \
  } while (0)

// B-fragment pair into DST: rows wc*64 + (NB..NB+1)*16 + lcol, both kk halves.
#define LDB2T(DST, BBUF, NB)                                             \
  do {                                                                   \
    _Pragma("unroll") for (int n_ = 0; n_ < 2; ++n_) {                   \
      const int br_ = wc * 64 + ((NB) + n_) * 16 + lcol;                 \
      const unsigned short* bp_ = (BBUF) + br_ * BK;                     \
      DST[n_][0] = *(const bf16x8*)(bp_ + (pc0 << 3));                   \
      DST[n_][1] = *(const bf16x8*)(bp_ + ((pc0 ^ 4) << 3));             \
    }                                                                    \
  } while (0)

// One C-quadrant x K=64: 4m x 2n x 2kk = 16 MFMA.
#define MM4(AF, BF, MB, NB)                                                 \
  do {                                                                      \
    _Pragma("unroll") for (int m_ = 0; m_ < 4; ++m_)                        \
    _Pragma("unroll") for (int n_ = 0; n_ < 2; ++n_)                        \
    _Pragma("unroll") for (int x_ = 0; x_ < 2; ++x_)                        \
      acc[(MB) + m_][(NB) + n_] = __builtin_amdgcn_mfma_f32_16x16x32_bf16(  \
          AF[m_][x_], BF[n_][x_], acc[(MB) + m_][(NB) + n_], 0, 0, 0);      \
  } while (0)

// Stage A half H (rows {H*64+wid*8+rl, 128+H*64+wid*8+rl}) of K-tile KT.
#define STAGE_A(H, DST, KT)                                                 \
  do {                                                                      \
    gload_lds16(agA + (size_t)((H) * 64) * H_DIM + (KT) * 64,               \
                (DST) + ((H) * 64 + wid * 8) * BK);                         \
    gload_lds16(agA + (size_t)((H) * 64 + 128) * H_DIM + (KT) * 64,         \
                (DST) + ((H) * 64 + 128 + wid * 8) * BK);                   \
  } while (0)

// Stage B strip S of K-tile KT.
#define STAGE_B(S, DST, KT)                                                 \
  do {                                                                      \
    gload_lds16(bgB0 + (size_t)((S) * 32) * H_DIM + (KT) * 64,              \
                (DST) + (bq0 + (S) * 32) * BK);                             \
    gload_lds16(bgB1 + (size_t)((S) * 32) * H_DIM + (KT) * 64,              \
                (DST) + (bq1 + (S) * 32) * BK);                             \
  } while (0)

// One K-tile, 4 snake phases, 1 barrier each. Reads for phase p+1 issued in
// tail of phase p (after MFMA), covered by the VMW ledger in the header.
#define KTILE(KT, AC, BC, AO, BO)                                        \
  do {                                                                   \
    /* P0: Q(lo-m, lo-n) — af=lo(KT), bfL(KT) read in prev P3 tail */    \
    LGKM0();                                                             \
    __builtin_amdgcn_s_setprio(1);                                       \
    MM4(af, bfL, 0, 0);                                                  \
    __builtin_amdgcn_s_setprio(0);                                       \
    LDB2T(bfH, BC, 2);                /* bf_hi(KT) for P1 */             \
    if ((KT) + 1 < NKT) STAGE_A(1, AO, (KT) + 1);                        \
    SB0();                                                               \
    BAR();                                                               \
    /* P1: Q(lo-m, hi-n) */                                              \
    LGKM0();                                                             \
    __builtin_amdgcn_s_setprio(1);                                       \
    MM4(af, bfH, 0, 2);                                                  \
    __builtin_amdgcn_s_setprio(0);                                       \
    LDA4T(af, AC, 4);                 /* af_hi(KT) for P2/P3 */          \
    if ((KT) + 1 < NKT) STAGE_B(1, BO, (KT) + 1);                        \
    SB0();                                                               \
    BAR();                                                               \
    /* P2: Q(hi-m, hi-n) */                                              \
    LGKM0();                                                             \
    __builtin_amdgcn_s_setprio(1);                                       \
    MM4(af, bfH, 4, 2);                                                  \
    __builtin_amdgcn_s_setprio(0);                                       \
    if ((KT) + 2 < NKT) {                                                \
      STAGE_A(0, AC, (KT) + 2);                                          \
      STAGE_B(0, BC, (KT) + 2);                                          \
      VMW(8);  /* retire A0(KT+1),B0(KT+1) for P3-tail reads */          \
    } else if ((KT) + 2 == NKT) {                                        \
      VMW(4);                                                            \
    }                                                                    \
    SB0();                                                               \
    BAR();                                                               \
    /* P3: Q(hi-m, lo-n) */                                              \
    LGKM0();                                                             \
    __builtin_amdgcn_s_setprio(1);                                       \
    MM4(af, bfL, 4, 0);                                                  \
    __builtin_amdgcn_s_setprio(0);                                       \
    if ((KT) + 1 < NKT) {                                                \
      LDA4T(af, AO, 0);               /* af_lo(KT+1) */                  \
      LDB2T(bfL, BO, 0);              /* bf_lo(KT+1) */                  \
      if ((KT) + 2 < NKT) VMW(4);  /* retire A1(KT+1),B1(KT+1) */        \
      else VMW(0);                 /* KT==NKT-2: drain for last tile */  \
    }                                                                    \
    SB0();                                                               \
    BAR();                                                               \
  } while (0)

__global__ __launch_bounds__(512, 2) void scl_gemm(
    const unsigned short* __restrict__ xb, const int* __restrict__ subject_id,
    const unsigned short* __restrict__ wb, const float* __restrict__ bias,
    float* __restrict__ out) {
  __shared__ __align__(16) unsigned short As[2][BM * BK];  // 64 KiB
  __shared__ __align__(16) unsigned short Bs[2][BN * BK];  // 64 KiB

  const int tid = threadIdx.x;
  const int lane = tid & 63;
  const int wid = tid >> 6;   // 0..7
  const int wr = wid >> 2;    // 0..1  (M half)
  const int wc = wid & 3;     // 0..3  (N quarter)
  const int lcol = lane & 15;
  const int lq = lane >> 4;   // 0..3
  const int rl = lane >> 3;   // 0..7 (staging row-in-group)
  const int pc0 = lq ^ (lane & 7);  // phys chunk for kk=0 (XOR swizzle)

  // XCD-grouped bijective block map: xcd = bid&7 owns batches 4*xcd..4*xcd+3.
  const int bid = blockIdx.x;
  const int b = (bid & 7) * 4 + ((bid >> 3) & 3);
  const int t = bid >> 5;          // 0..7
  const int n0 = (t & 1) * BM;
  const int o0 = (t >> 1) * BN;
  const int sid = subject_id[b];

  // Staging global bases. Lane L covers phys chunk L&7 of row rl;
  // logical chunk = (L&7)^rl (row&7 == rl since all row bases are x8).
  const int skc = ((lane & 7) ^ rl) << 3;
  const unsigned short* agA =
      xb + (size_t)(b * N_DIM + n0 + wid * 8 + rl) * H_DIM + skc;
  const int bq0 = ((wid * 2) >> 2) * 64 + ((wid * 2) & 3) * 8;
  const int bq1 = ((wid * 2 + 1) >> 2) * 64 + ((wid * 2 + 1) & 3) * 8;
  const unsigned short* bgB0 =
      wb + (size_t)(sid * O_DIM + o0 + bq0 + rl) * H_DIM + skc;
  const unsigned short* bgB1 =
      wb + (size_t)(sid * O_DIM + o0 + bq1 + rl) * H_DIM + skc;

  unsigned short* const As0 = &As[0][0];
  unsigned short* const As1 = &As[1][0];
  unsigned short* const Bs0 = &Bs[0][0];
  unsigned short* const Bs1 = &Bs[1][0];

  f32x4 acc[8][4];
#pragma unroll
  for (int mi = 0; mi < 8; ++mi)
#pragma unroll
    for (int ni = 0; ni < 4; ++ni) {
      f32x4 z = {0.f, 0.f, 0.f, 0.f};
      acc[mi][ni] = z;
    }

  bf16x8 af[4][2];   // ping-pong: lo(kt) during P0/P1, hi(kt) during P2/P3
  bf16x8 bfL[2][2];  // B lo-n pair, live P0..P3
  bf16x8 bfH[2][2];  // B hi-n pair, live P1..P2

  // Prologue stage stream (loads 1..12): A0(0) B0(0) A1(0) B1(0) A0(1) B0(1).
  STAGE_A(0, As0, 0);
  STAGE_B(0, Bs0, 0);
  STAGE_A(1, As0, 0);
  STAGE_B(1, Bs0, 0);
  STAGE_A(0, As1, 1);
  STAGE_B(0, Bs1, 1);
  VMW(4);  // retire A0(0),B0(0),A1(0),B1(0); leave A0(1),B0(1) in flight
  BAR();
  LDA4T(af, As0, 0);   // af_lo(0)
  LDB2T(bfL, Bs0, 0);  // bf_lo(0)
  SB0();

#pragma unroll 1
  for (int kt = 0; kt < NKT; kt += 2) {
    KTILE(kt, As0, Bs0, As1, Bs1);
    KTILE(kt + 1, As1, Bs1, As0, Bs0);
  }

  // Epilogue: C/D layout col = lane&15, row = (lane>>4)*4 + reg.
  float bv[4];
#pragma unroll
  for (int ni = 0; ni < 4; ++ni)
    bv[ni] = bias[sid * O_DIM + o0 + wc * 64 + ni * 16 + lcol];

  float* outb =
      out + (size_t)(b * N_DIM + n0 + wr * 128) * O_DIM + o0 + wc * 64 + lcol;
#pragma unroll
  for (int mi = 0; mi < 8; ++mi) {
#pragma unroll
    for (int r = 0; r < 4; ++r) {
      float* orow = outb + (size_t)(mi * 16 + lq * 4 + r) * O_DIM;
#pragma unroll
      for (int ni = 0; ni < 4; ++ni)
        orow[ni * 16] = acc[mi][ni][r] + bv[ni];
    }
  }
}

extern "C" void kernel_launch(void* const* d_in, const int* in_sizes, int n_in,
                              void* d_out, int out_size, void* d_ws, size_t ws_size,
                              hipStream_t stream) {
  const float* x = (const float*)d_in[0];
  const int* subject_id = (const int*)d_in[1];
  const float* weight = (const float*)d_in[2];
  const float* bias = (const float*)d_in[3];
  float* out = (float*)d_out;

  unsigned short* xb = (unsigned short*)d_ws;                       // 32 MiB
  unsigned short* wb = (unsigned short*)((char*)d_ws + XB_BYTES);   // 16 MiB

  cvt_kernel<<<6144, 256, 0, stream>>>(x, weight, xb, wb);

  scl_gemm<<<256, 512, 0, stream>>>(xb, subject_id, wb, bias, out);
}